// Round 19
// baseline (220.502 us; speedup 1.0000x reference)
//
#include <hip/hip_runtime.h>

#define N_NODES 100000
#define N_EDGES 1600000
#define DIM 128
#define ACT 512
#define NG 64
#define CHUNK 128
#define NBUK 782            // ceil(N_NODES/CHUNK)
#define NBUK2 (2 * NBUK)
#define EB 8192             // edges per partition block
#define NBLK_E 196          // ceil(N_EDGES/EB)
#define EPT 8               // edges per thread in bfill (EB/1024)
#define UP 136              // bf16 row pitch for uT/cbf (16B-aligned rows)
#define ZP 132              // fp32 ztile pitch (bank-conflict-free staging)
#define NPART 8             // zred partial reducers per output

typedef __attribute__((ext_vector_type(8))) short bf16x8;
typedef __attribute__((ext_vector_type(4))) float f32x4;

__device__ __forceinline__ unsigned short f2bf(float f) {
    union { float f; unsigned int i; } v;
    v.f = f;
    unsigned int i = v.i;
    i += 0x7fffu + ((i >> 16) & 1u);   // RNE
    return (unsigned short)(i >> 16);
}
__device__ __forceinline__ float bflo(unsigned int u) {
    union { unsigned int i; float f; } v;
    v.i = u << 16;
    return v.f;
}
__device__ __forceinline__ float bfhi(unsigned int u) {
    union { unsigned int i; float f; } v;
    v.i = u & 0xffff0000u;
    return v.f;
}

// ---------------- chunk-granular edge partition, both sides ----------------

__global__ __launch_bounds__(512) void k_hist(const int* __restrict__ src,
                                              const int* __restrict__ dst,
                                              int* __restrict__ hist) {
    __shared__ int lh[NBUK2];
    int t = threadIdx.x;
    for (int i = t; i < NBUK2; i += 512) lh[i] = 0;
    __syncthreads();
    int e0 = blockIdx.x * EB;
    int e1 = min(e0 + EB, N_EDGES);
    for (int i = e0 + t; i < e1; i += 512) {
        atomicAdd(&lh[dst[i] >> 7], 1);
        atomicAdd(&lh[NBUK + (src[i] >> 7)], 1);
    }
    __syncthreads();
    int* row = hist + (size_t)blockIdx.x * NBUK2;
    for (int i = t; i < NBUK2; i += 512) row[i] = lh[i];
}

// per-bucket scan over the 196 partition blocks
__global__ __launch_bounds__(256) void k_bscanA(int* __restrict__ hist,
                                                int* __restrict__ colsum) {
    __shared__ int s[256];
    int b = blockIdx.x, t = threadIdx.x;
    int v = (t < NBLK_E) ? hist[(size_t)t * NBUK2 + b] : 0;
    s[t] = v;
    __syncthreads();
    for (int off = 1; off < 256; off <<= 1) {
        int add = (t >= off) ? s[t - off] : 0;
        __syncthreads();
        s[t] += add;
        __syncthreads();
    }
    if (t < NBLK_E) hist[(size_t)t * NBUK2 + b] = s[t] - v;
    if (t == 255) colsum[b] = s[255];
}

__global__ __launch_bounds__(1024) void k_bscanB(const int* __restrict__ colsum,
                                                 int* __restrict__ off_d,
                                                 int* __restrict__ off_s) {
    __shared__ int s[1024];
    int t = threadIdx.x;
    int v = (t < NBUK) ? colsum[t] : 0;
    s[t] = v;
    __syncthreads();
    for (int off = 1; off < 1024; off <<= 1) {
        int add = (t >= off) ? s[t - off] : 0;
        __syncthreads();
        s[t] += add;
        __syncthreads();
    }
    if (t < NBUK) off_d[t] = s[t] - v;
    if (t == 1023) off_d[NBUK] = s[1023];
    __syncthreads();
    int v2 = (t < NBUK) ? colsum[NBUK + t] : 0;
    s[t] = v2;
    __syncthreads();
    for (int off = 1; off < 1024; off <<= 1) {
        int add = (t >= off) ? s[t - off] : 0;
        __syncthreads();
        s[t] += add;
        __syncthreads();
    }
    if (t < NBUK) off_s[t] = s[t] - v2;
    if (t == 1023) off_s[NBUK] = s[1023];
}

// LDS-reordered dual fill (bucket-sort per block, linear copy-out)
__global__ __launch_bounds__(1024) void k_bfill(const int* __restrict__ src,
                                                const int* __restrict__ dst,
                                                const int* __restrict__ batch,
                                                const int* __restrict__ hist,
                                                const int* __restrict__ off_d,
                                                const int* __restrict__ off_s,
                                                int* __restrict__ edata_d,
                                                int* __restrict__ edata_s) {
    __shared__ int gbase[NBUK];
    __shared__ int lofs[NBUK];
    __shared__ int stage[EB];
    __shared__ unsigned short bkt[EB];
    __shared__ int stmp[1024];
    int t = threadIdx.x;
    int blk = blockIdx.x;
    int e0 = blk * EB;
    int e1 = min(e0 + EB, N_EDGES);
    int ne = e1 - e0;
    const int* row = hist + (size_t)blk * NBUK2;

    int pay[EPT];
    unsigned short pb[EPT], pr[EPT];

    // ================= side D =================
    for (int i = t; i < NBUK; i += 1024) { gbase[i] = row[i] + off_d[i]; lofs[i] = 0; }
    __syncthreads();
#pragma unroll
    for (int k = 0; k < EPT; ++k) {
        int i = e0 + k * 1024 + t;
        if (i < e1) {
            int s = src[i], d = dst[i];
            int b = d >> 7;
            int r = atomicAdd(&lofs[b], 1);
            pay[k] = ((d & 127) << 17) | s;
            pb[k] = (unsigned short)b;
            pr[k] = (unsigned short)r;
        }
    }
    __syncthreads();
    {
        int v = (t < NBUK) ? lofs[t] : 0;
        stmp[t] = v;
        __syncthreads();
        for (int off = 1; off < 1024; off <<= 1) {
            int add = (t >= off) ? stmp[t - off] : 0;
            __syncthreads();
            stmp[t] += add;
            __syncthreads();
        }
        if (t < NBUK) lofs[t] = stmp[t] - v;
    }
    __syncthreads();
#pragma unroll
    for (int k = 0; k < EPT; ++k) {
        int i = e0 + k * 1024 + t;
        if (i < e1) {
            int pos = lofs[pb[k]] + pr[k];
            stage[pos] = pay[k];
            bkt[pos] = pb[k];
        }
    }
    __syncthreads();
#pragma unroll
    for (int k = 0; k < EPT; ++k) {
        int j = k * 1024 + t;
        if (j < ne) {
            int b = bkt[j];
            edata_d[gbase[b] + (j - lofs[b])] = stage[j];
        }
    }
    __syncthreads();

    // ================= side S =================
    for (int i = t; i < NBUK; i += 1024) { gbase[i] = row[NBUK + i] + off_s[i]; lofs[i] = 0; }
    __syncthreads();
#pragma unroll
    for (int k = 0; k < EPT; ++k) {
        int i = e0 + k * 1024 + t;
        if (i < e1) {
            int s = src[i], d = dst[i];
            int g = batch[d];
            int b = s >> 7;
            int r = atomicAdd(&lofs[b], 1);
            pay[k] = ((s & 127) << 23) | (g << 17) | d;
            pb[k] = (unsigned short)b;
            pr[k] = (unsigned short)r;
        }
    }
    __syncthreads();
    {
        int v = (t < NBUK) ? lofs[t] : 0;
        stmp[t] = v;
        __syncthreads();
        for (int off = 1; off < 1024; off <<= 1) {
            int add = (t >= off) ? stmp[t - off] : 0;
            __syncthreads();
            stmp[t] += add;
            __syncthreads();
        }
        if (t < NBUK) lofs[t] = stmp[t] - v;
    }
    __syncthreads();
#pragma unroll
    for (int k = 0; k < EPT; ++k) {
        int i = e0 + k * 1024 + t;
        if (i < e1) {
            int pos = lofs[pb[k]] + pr[k];
            stage[pos] = pay[k];
            bkt[pos] = pb[k];
        }
    }
    __syncthreads();
#pragma unroll
    for (int k = 0; k < EPT; ++k) {
        int j = k * 1024 + t;
        if (j < ne) {
            int b = bkt[j];
            edata_s[gbase[b] + (j - lofs[b])] = stage[j];
        }
    }
}

// ---------------- per-chunk in-degree -> dis, xd ----------------

__global__ __launch_bounds__(256) void k_indeg(const int* __restrict__ edata_d,
                                               const int* __restrict__ off_d,
                                               const float* __restrict__ x,
                                               float* __restrict__ dis,
                                               float4* __restrict__ xd) {
    __shared__ int cnt[CHUNK];
    int t = threadIdx.x;
    int b = blockIdx.x;
    if (t < CHUNK) cnt[t] = 0;
    __syncthreads();
    int e0 = off_d[b], e1 = off_d[b + 1];
    for (int i = e0 + t; i < e1; i += 256) atomicAdd(&cnt[edata_d[i] >> 17], 1);
    __syncthreads();
    if (t < CHUNK) {
        int node = b * CHUNK + t;
        if (node < N_NODES) {
            float d = rsqrtf((float)(cnt[t] + 1));
            dis[node] = d;
            float4 p;
            p.x = x[node * 3 + 0] * d;
            p.y = x[node * 3 + 1] * d;
            p.z = x[node * 3 + 2] * d;
            p.w = d;
            xd[node] = p;
        }
    }
}

// ---------------- layer-1 aggregation per dst chunk; agg.w = dis ----------------

__global__ __launch_bounds__(256) void k_agg(const int* __restrict__ edata_d,
                                             const int* __restrict__ off_d,
                                             const float4* __restrict__ xd,
                                             float4* __restrict__ agg) {
    __shared__ float ax[CHUNK], ay[CHUNK], az[CHUNK];
    int t = threadIdx.x;
    int b = blockIdx.x;
    if (t < CHUNK) { ax[t] = 0.f; ay[t] = 0.f; az[t] = 0.f; }
    __syncthreads();
    int e0 = off_d[b], e1 = off_d[b + 1];
    int i = e0 + t;
    for (; i + 1792 < e1; i += 2048) {
        int p[8];
        float4 y[8];
#pragma unroll
        for (int k = 0; k < 8; ++k) p[k] = edata_d[i + k * 256];
#pragma unroll
        for (int k = 0; k < 8; ++k) y[k] = xd[p[k] & 0x1FFFF];
#pragma unroll
        for (int k = 0; k < 8; ++k) {
            int dl = p[k] >> 17;
            atomicAdd(&ax[dl], y[k].x);
            atomicAdd(&ay[dl], y[k].y);
            atomicAdd(&az[dl], y[k].z);
        }
    }
    for (; i < e1; i += 256) {
        int p = edata_d[i];
        int dl = p >> 17;
        float4 y = xd[p & 0x1FFFF];
        atomicAdd(&ax[dl], y.x);
        atomicAdd(&ay[dl], y.y);
        atomicAdd(&az[dl], y.z);
    }
    __syncthreads();
    if (t < CHUNK) {
        int node = b * CHUNK + t;
        if (node < N_NODES) {
            float4 self = xd[node];
            float d = self.w;
            float4 o;
            o.x = (ax[t] + self.x) * d;
            o.y = (ay[t] + self.y) * d;
            o.z = (az[t] + self.z) * d;
            o.w = d;
            agg[node] = o;
        }
    }
}

// ---------------- coefficient build + MFMA z contraction (src chunks) ----------------
// ags staged as bf16x4 (1 KB instead of 2 KB) -> LDS 53248 B -> 3 blocks/CU.

__global__ __launch_bounds__(256) void k_zgemm(const float4* __restrict__ agg,
                                               const int* __restrict__ edata_s,
                                               const int* __restrict__ off_s,
                                               const int* __restrict__ batch,
                                               const float* __restrict__ dis,
                                               const float* __restrict__ W1,
                                               const float* __restrict__ b1,
                                               float* __restrict__ zpart) {
    __shared__ __align__(16) char smem[(DIM + NG) * UP * 2];   // 52224 B
    __shared__ uint2 agb[CHUNK];                               // bf16x4: (x|y, z|dis), 1 KB
    float* ctile = (float*)smem;                                  // [CHUNK][NG] fp32, 32 KB
    unsigned short* uT = (unsigned short*)smem;                   // [DIM][UP] bf16 (overlays ctile)
    float* ztile = (float*)smem;                                  // [NG][ZP] fp32 (overlays uT post-MFMA)
    unsigned short* cbf = (unsigned short*)(smem + DIM * UP * 2); // [NG][UP] bf16

    int t = threadIdx.x;
    int wave = t >> 6, lane = t & 63;
    int q = lane >> 4, l15 = lane & 15;
    int blk = blockIdx.x;
    int base = blk * CHUNK;

    for (int i = t; i < CHUNK * NG; i += 256) ctile[i] = 0.f;
    if (t < CHUNK) {
        int s = base + t;
        float4 a = (s < N_NODES) ? agg[s] : (float4){0.f, 0.f, 0.f, 0.f};
        uint2 p;
        p.x = (unsigned int)f2bf(a.x) | ((unsigned int)f2bf(a.y) << 16);
        p.y = (unsigned int)f2bf(a.z) | ((unsigned int)f2bf(a.w) << 16);
        agb[t] = p;
    }
    __syncthreads();
    // edge phase: ctile[sl][g] += dis_s * dis_d, x8 unrolled for gather MLP
    int e0 = off_s[blk], e1 = off_s[blk + 1];
    int i = e0 + t;
    for (; i + 1792 < e1; i += 2048) {
        int p[8];
        float dd[8];
#pragma unroll
        for (int k = 0; k < 8; ++k) p[k] = edata_s[i + k * 256];
#pragma unroll
        for (int k = 0; k < 8; ++k) dd[k] = dis[p[k] & 0x1FFFF];
#pragma unroll
        for (int k = 0; k < 8; ++k) {
            int sl = p[k] >> 23;
            float ds = bfhi(agb[sl].y);
            atomicAdd(&ctile[sl * NG + ((p[k] >> 17) & 63)], ds * dd[k]);
        }
    }
    for (; i < e1; i += 256) {
        int p = edata_s[i];
        int sl = p >> 23;
        float ds = bfhi(agb[sl].y);
        atomicAdd(&ctile[sl * NG + ((p >> 17) & 63)], ds * dis[p & 0x1FFFF]);
    }
    if (t < CHUNK) {
        int s = base + t;
        if (s < N_NODES) {
            float w = bfhi(agb[t].y);
            atomicAdd(&ctile[t * NG + batch[s]], w * w);
        }
    }
    __syncthreads();
    // transpose-convert: cbf[g][s] = bf16(ctile[s][g])
    for (int i2 = t; i2 < CHUNK * NG; i2 += 256) {
        int g = i2 & 63, s = i2 >> 6;
        cbf[g * UP + s] = f2bf(ctile[i2]);
    }
    __syncthreads();
    // u compute -> bf16 uT[n][s] (overlays ctile)
    {
        int n = t >> 1;
        int sh = (t & 1) * 64;
        float w0 = W1[n], w1 = W1[DIM + n], w2 = W1[2 * DIM + n], bb = b1[n];
        for (int sp = 0; sp < 64; sp += 2) {
            uint2 pa = agb[sh + sp];
            uint2 pbv = agb[sh + sp + 1];
            float u0 = fmaxf(fmaf(bflo(pa.x), w0, fmaf(bfhi(pa.x), w1, fmaf(bflo(pa.y), w2, bb))), 0.f);
            float u1 = fmaxf(fmaf(bflo(pbv.x), w0, fmaf(bfhi(pbv.x), w1, fmaf(bflo(pbv.y), w2, bb))), 0.f);
            unsigned int pk = (unsigned int)f2bf(u0) | ((unsigned int)f2bf(u1) << 16);
            *(unsigned int*)&uT[n * UP + sh + sp] = pk;
        }
    }
    __syncthreads();
    // MFMA: wave w owns n-tiles {2w, 2w+1} x 4 g-tiles
    f32x4 acc[2][4];
#pragma unroll
    for (int mi = 0; mi < 2; ++mi)
#pragma unroll
        for (int nt = 0; nt < 4; ++nt) acc[mi][nt] = (f32x4){0.f, 0.f, 0.f, 0.f};
#pragma unroll
    for (int ks = 0; ks < 4; ++ks) {
        int s0 = ks * 32 + q * 8;
        union { uint4 r; bf16x8 v; } A0, A1, B;
        A0.r = *(const uint4*)&uT[((2 * wave + 0) * 16 + l15) * UP + s0];
        A1.r = *(const uint4*)&uT[((2 * wave + 1) * 16 + l15) * UP + s0];
#pragma unroll
        for (int nt = 0; nt < 4; ++nt) {
            B.r = *(const uint4*)&cbf[(nt * 16 + l15) * UP + s0];
            acc[0][nt] = __builtin_amdgcn_mfma_f32_16x16x32_bf16(A0.v, B.v, acc[0][nt], 0, 0, 0);
            acc[1][nt] = __builtin_amdgcn_mfma_f32_16x16x32_bf16(A1.v, B.v, acc[1][nt], 0, 0, 0);
        }
    }
    __syncthreads();   // uT reads done; reuse as ztile
#pragma unroll
    for (int mi = 0; mi < 2; ++mi) {
#pragma unroll
        for (int nt = 0; nt < 4; ++nt) {
            int g = nt * 16 + l15;
#pragma unroll
            for (int r = 0; r < 4; ++r) {
                int n = (2 * wave + mi) * 16 + q * 4 + r;
                ztile[g * ZP + n] = acc[mi][nt][r];
            }
        }
    }
    __syncthreads();
    float* zp = zpart + (size_t)blk * (NG * DIM);
    for (int i2 = t; i2 < NG * DIM; i2 += 256)
        zp[i2] = ztile[(i2 >> 7) * ZP + (i2 & 127)];
}

// ---------------- two-stage zpart reduction ----------------

__global__ __launch_bounds__(256) void k_zred1(const float* __restrict__ zpart,
                                               float* __restrict__ zpart2) {
    int id = blockIdx.x * 256 + threadIdx.x;      // [0, NPART*8192)
    int i = id & (NG * DIM - 1);
    int p = id >> 13;
    int b0 = p * 98;
    int b1 = min(b0 + 98, NBUK);
    const float* base = zpart + i;
    float s0 = 0.f, s1 = 0.f, s2 = 0.f, s3 = 0.f;
    int b = b0;
    for (; b + 3 < b1; b += 4) {
        s0 += base[(size_t)(b + 0) * (NG * DIM)];
        s1 += base[(size_t)(b + 1) * (NG * DIM)];
        s2 += base[(size_t)(b + 2) * (NG * DIM)];
        s3 += base[(size_t)(b + 3) * (NG * DIM)];
    }
    for (; b < b1; ++b) s0 += base[(size_t)b * (NG * DIM)];
    zpart2[(size_t)p * (NG * DIM) + i] = (s0 + s1) + (s2 + s3);
}

// ---------------- head: poolmix (8-way partial sum) + final ----------------

__global__ __launch_bounds__(128) void k_poolmix(const float* __restrict__ zpart2,
                                                 const float* __restrict__ W2,
                                                 const float* __restrict__ b2,
                                                 const int* __restrict__ batch,
                                                 float* __restrict__ embed) {
    __shared__ float zr[DIM];
    __shared__ int se[2];
    int g = blockIdx.x;
    int t = threadIdx.x;
    if (t < 2) {
        int target = g + t;
        int lo = 0, hi = N_NODES;
        while (lo < hi) {
            int mid = (lo + hi) >> 1;
            if (batch[mid] < target) lo = mid + 1; else hi = mid;
        }
        se[t] = lo;
    }
    {
        const float* base = zpart2 + g * DIM + t;
        float acc = 0.f;
#pragma unroll
        for (int p = 0; p < NPART; ++p) acc += base[(size_t)p * (NG * DIM)];
        zr[t] = acc;
    }
    __syncthreads();
    float inv = 1.0f / fmaxf((float)(se[1] - se[0]), 1.0f);
    float acc = 0.f;
#pragma unroll 4
    for (int k = 0; k < DIM; ++k) acc = fmaf(zr[k], W2[k * DIM + t], acc);
    embed[g * DIM + t] = acc * inv + b2[t];
}

__global__ __launch_bounds__(128) void k_final(const float* __restrict__ embed,
                                               const float* __restrict__ Wf,
                                               const float* __restrict__ bf,
                                               float* __restrict__ out) {
    int id = blockIdx.x * 128 + threadIdx.x;
    int g = id >> 9, a = id & 511;
    const float* e = embed + g * DIM;
    float s0 = 0.f, s1 = 0.f, s2 = 0.f, s3 = 0.f;
#pragma unroll
    for (int c = 0; c < DIM; c += 4) {
        s0 = fmaf(e[c + 0], Wf[(c + 0) * ACT + a], s0);
        s1 = fmaf(e[c + 1], Wf[(c + 1) * ACT + a], s1);
        s2 = fmaf(e[c + 2], Wf[(c + 2) * ACT + a], s2);
        s3 = fmaf(e[c + 3], Wf[(c + 3) * ACT + a], s3);
    }
    out[id] = (s0 + s1) + (s2 + s3) + bf[a];
}

// ---------------- launch ----------------

static inline size_t align256(size_t x) { return (x + 255) & ~(size_t)255; }

extern "C" void kernel_launch(void* const* d_in, const int* in_sizes, int n_in,
                              void* d_out, int out_size, void* d_ws, size_t ws_size,
                              hipStream_t stream) {
    const float* x  = (const float*)d_in[0];
    const int*   ei = (const int*)d_in[1];
    const int*   batch = (const int*)d_in[2];
    const float* W1 = (const float*)d_in[3];
    const float* b1 = (const float*)d_in[4];
    const float* W2 = (const float*)d_in[5];
    const float* b2 = (const float*)d_in[6];
    const float* Wf = (const float*)d_in[7];
    const float* bf = (const float*)d_in[8];
    float* out = (float*)d_out;

    const int* src = ei;
    const int* dst = ei + N_EDGES;

    char* ws = (char*)d_ws;
    size_t off = 0;
    int*   hist    = (int*)(ws + off);   off = align256(off + (size_t)NBLK_E * NBUK2 * 4);
    int*   colsum  = (int*)(ws + off);   off = align256(off + NBUK2 * 4);
    int*   off_d   = (int*)(ws + off);   off = align256(off + (NBUK + 1) * 4);
    int*   off_s   = (int*)(ws + off);   off = align256(off + (NBUK + 1) * 4);
    int*   edata_d = (int*)(ws + off);   off = align256(off + (size_t)N_EDGES * 4);
    int*   edata_s = (int*)(ws + off);   off = align256(off + (size_t)N_EDGES * 4);
    float* dis     = (float*)(ws + off); off = align256(off + N_NODES * 4);
    float4* xd     = (float4*)(ws + off); off = align256(off + (size_t)N_NODES * 16);
    float4* agg    = (float4*)(ws + off); off = align256(off + (size_t)N_NODES * 16);
    float* zpart   = (float*)(ws + off); off = align256(off + (size_t)NBUK * NG * DIM * 4);
    float* zpart2  = (float*)(ws + off); off = align256(off + (size_t)NPART * NG * DIM * 4);
    float* embed   = (float*)(ws + off); off = align256(off + NG * DIM * 4);

    k_hist<<<NBLK_E, 512, 0, stream>>>(src, dst, hist);
    k_bscanA<<<NBUK2, 256, 0, stream>>>(hist, colsum);
    k_bscanB<<<1, 1024, 0, stream>>>(colsum, off_d, off_s);
    k_bfill<<<NBLK_E, 1024, 0, stream>>>(src, dst, batch, hist, off_d, off_s, edata_d, edata_s);

    k_indeg<<<NBUK, 256, 0, stream>>>(edata_d, off_d, x, dis, xd);
    k_agg<<<NBUK, 256, 0, stream>>>(edata_d, off_d, xd, agg);
    k_zgemm<<<NBUK, 256, 0, stream>>>(agg, edata_s, off_s, batch, dis, W1, b1, zpart);
    k_zred1<<<NPART * NG * DIM / 256, 256, 0, stream>>>(zpart, zpart2);

    k_poolmix<<<NG, 128, 0, stream>>>(zpart2, W2, b2, batch, embed);
    k_final<<<NG * ACT / 128, 128, 0, stream>>>(embed, Wf, bf, out);
}

// Round 20
// 218.534 us; speedup vs baseline: 1.0090x; 1.0090x over previous
//
#include <hip/hip_runtime.h>

#define N_NODES 100000
#define N_EDGES 1600000
#define DIM 128
#define ACT 512
#define NG 64
#define CHUNK 128
#define NBUK 782            // ceil(N_NODES/CHUNK)
#define NBUK2 (2 * NBUK)
#define EB 8192             // edges per partition block
#define NBLK_E 196          // ceil(N_EDGES/EB)
#define EPT 8               // edges per thread in bfill (EB/1024)
#define UP 136              // bf16 row pitch for uT/cbf (16B-aligned rows)
#define ZP 132              // fp32 ztile pitch (bank-conflict-free staging)
#define NPART 8             // zred partial reducers per output

typedef __attribute__((ext_vector_type(8))) short bf16x8;
typedef __attribute__((ext_vector_type(4))) float f32x4;

__device__ __forceinline__ unsigned short f2bf(float f) {
    union { float f; unsigned int i; } v;
    v.f = f;
    unsigned int i = v.i;
    i += 0x7fffu + ((i >> 16) & 1u);   // RNE
    return (unsigned short)(i >> 16);
}
__device__ __forceinline__ float bflo(unsigned int u) {
    union { unsigned int i; float f; } v;
    v.i = u << 16;
    return v.f;
}
__device__ __forceinline__ float bfhi(unsigned int u) {
    union { unsigned int i; float f; } v;
    v.i = u & 0xffff0000u;
    return v.f;
}

// ---------------- chunk-granular edge partition, both sides ----------------

__global__ __launch_bounds__(512) void k_hist(const int* __restrict__ src,
                                              const int* __restrict__ dst,
                                              int* __restrict__ hist) {
    __shared__ int lh[NBUK2];
    int t = threadIdx.x;
    for (int i = t; i < NBUK2; i += 512) lh[i] = 0;
    __syncthreads();
    const int4* src4 = (const int4*)src;
    const int4* dst4 = (const int4*)dst;
    int q0 = blockIdx.x * (EB / 4);
    int q1 = min(q0 + EB / 4, N_EDGES / 4);
    for (int i = q0 + t; i < q1; i += 512) {
        int4 d4 = dst4[i];
        int4 s4 = src4[i];
        atomicAdd(&lh[d4.x >> 7], 1);
        atomicAdd(&lh[d4.y >> 7], 1);
        atomicAdd(&lh[d4.z >> 7], 1);
        atomicAdd(&lh[d4.w >> 7], 1);
        atomicAdd(&lh[NBUK + (s4.x >> 7)], 1);
        atomicAdd(&lh[NBUK + (s4.y >> 7)], 1);
        atomicAdd(&lh[NBUK + (s4.z >> 7)], 1);
        atomicAdd(&lh[NBUK + (s4.w >> 7)], 1);
    }
    __syncthreads();
    int* row = hist + (size_t)blockIdx.x * NBUK2;
    for (int i = t; i < NBUK2; i += 512) row[i] = lh[i];
}

// per-bucket scan over the 196 partition blocks
__global__ __launch_bounds__(256) void k_bscanA(int* __restrict__ hist,
                                                int* __restrict__ colsum) {
    __shared__ int s[256];
    int b = blockIdx.x, t = threadIdx.x;
    int v = (t < NBLK_E) ? hist[(size_t)t * NBUK2 + b] : 0;
    s[t] = v;
    __syncthreads();
    for (int off = 1; off < 256; off <<= 1) {
        int add = (t >= off) ? s[t - off] : 0;
        __syncthreads();
        s[t] += add;
        __syncthreads();
    }
    if (t < NBLK_E) hist[(size_t)t * NBUK2 + b] = s[t] - v;
    if (t == 255) colsum[b] = s[255];
}

__global__ __launch_bounds__(1024) void k_bscanB(const int* __restrict__ colsum,
                                                 int* __restrict__ off_d,
                                                 int* __restrict__ off_s) {
    __shared__ int s[1024];
    int t = threadIdx.x;
    int v = (t < NBUK) ? colsum[t] : 0;
    s[t] = v;
    __syncthreads();
    for (int off = 1; off < 1024; off <<= 1) {
        int add = (t >= off) ? s[t - off] : 0;
        __syncthreads();
        s[t] += add;
        __syncthreads();
    }
    if (t < NBUK) off_d[t] = s[t] - v;
    if (t == 1023) off_d[NBUK] = s[1023];
    __syncthreads();
    int v2 = (t < NBUK) ? colsum[NBUK + t] : 0;
    s[t] = v2;
    __syncthreads();
    for (int off = 1; off < 1024; off <<= 1) {
        int add = (t >= off) ? s[t - off] : 0;
        __syncthreads();
        s[t] += add;
        __syncthreads();
    }
    if (t < NBUK) off_s[t] = s[t] - v2;
    if (t == 1023) off_s[NBUK] = s[1023];
}

// LDS-reordered dual fill (bucket-sort per block, linear copy-out).
// Thread owns 8 CONTIGUOUS edges -> 2x int4 loads per array per side.
__global__ __launch_bounds__(1024) void k_bfill(const int* __restrict__ src,
                                                const int* __restrict__ dst,
                                                const int* __restrict__ batch,
                                                const int* __restrict__ hist,
                                                const int* __restrict__ off_d,
                                                const int* __restrict__ off_s,
                                                int* __restrict__ edata_d,
                                                int* __restrict__ edata_s) {
    __shared__ int gbase[NBUK];
    __shared__ int lofs[NBUK];
    __shared__ int stage[EB];
    __shared__ unsigned short bkt[EB];
    __shared__ int stmp[1024];
    int t = threadIdx.x;
    int blk = blockIdx.x;
    int e0 = blk * EB;
    int e1 = min(e0 + EB, N_EDGES);
    int ne = e1 - e0;
    const int* row = hist + (size_t)blk * NBUK2;
    int my0 = e0 + t * EPT;   // contiguous 8 edges per thread

    int sv[EPT], dv[EPT];
    {
        const int4* s4 = (const int4*)(src + my0);
        const int4* d4 = (const int4*)(dst + my0);
        if (my0 + EPT <= e1) {
            int4 a = s4[0], b = s4[1];
            sv[0] = a.x; sv[1] = a.y; sv[2] = a.z; sv[3] = a.w;
            sv[4] = b.x; sv[5] = b.y; sv[6] = b.z; sv[7] = b.w;
            int4 c = d4[0], d = d4[1];
            dv[0] = c.x; dv[1] = c.y; dv[2] = c.z; dv[3] = c.w;
            dv[4] = d.x; dv[5] = d.y; dv[6] = d.z; dv[7] = d.w;
        } else {
#pragma unroll
            for (int k = 0; k < EPT; ++k) {
                int i = my0 + k;
                sv[k] = (i < e1) ? src[i] : 0;
                dv[k] = (i < e1) ? dst[i] : 0;
            }
        }
    }

    int pay[EPT];
    unsigned short pb[EPT], pr[EPT];

    // ================= side D =================
    for (int i = t; i < NBUK; i += 1024) { gbase[i] = row[i] + off_d[i]; lofs[i] = 0; }
    __syncthreads();
#pragma unroll
    for (int k = 0; k < EPT; ++k) {
        int i = my0 + k;
        if (i < e1) {
            int b = dv[k] >> 7;
            int r = atomicAdd(&lofs[b], 1);
            pay[k] = ((dv[k] & 127) << 17) | sv[k];
            pb[k] = (unsigned short)b;
            pr[k] = (unsigned short)r;
        }
    }
    __syncthreads();
    {
        int v = (t < NBUK) ? lofs[t] : 0;
        stmp[t] = v;
        __syncthreads();
        for (int off = 1; off < 1024; off <<= 1) {
            int add = (t >= off) ? stmp[t - off] : 0;
            __syncthreads();
            stmp[t] += add;
            __syncthreads();
        }
        if (t < NBUK) lofs[t] = stmp[t] - v;
    }
    __syncthreads();
#pragma unroll
    for (int k = 0; k < EPT; ++k) {
        int i = my0 + k;
        if (i < e1) {
            int pos = lofs[pb[k]] + pr[k];
            stage[pos] = pay[k];
            bkt[pos] = pb[k];
        }
    }
    __syncthreads();
#pragma unroll
    for (int k = 0; k < EPT; ++k) {
        int j = k * 1024 + t;
        if (j < ne) {
            int b = bkt[j];
            edata_d[gbase[b] + (j - lofs[b])] = stage[j];
        }
    }
    __syncthreads();

    // ================= side S =================
    for (int i = t; i < NBUK; i += 1024) { gbase[i] = row[NBUK + i] + off_s[i]; lofs[i] = 0; }
    __syncthreads();
#pragma unroll
    for (int k = 0; k < EPT; ++k) {
        int i = my0 + k;
        if (i < e1) {
            int g = batch[dv[k]];
            int b = sv[k] >> 7;
            int r = atomicAdd(&lofs[b], 1);
            pay[k] = ((sv[k] & 127) << 23) | (g << 17) | dv[k];
            pb[k] = (unsigned short)b;
            pr[k] = (unsigned short)r;
        }
    }
    __syncthreads();
    {
        int v = (t < NBUK) ? lofs[t] : 0;
        stmp[t] = v;
        __syncthreads();
        for (int off = 1; off < 1024; off <<= 1) {
            int add = (t >= off) ? stmp[t - off] : 0;
            __syncthreads();
            stmp[t] += add;
            __syncthreads();
        }
        if (t < NBUK) lofs[t] = stmp[t] - v;
    }
    __syncthreads();
#pragma unroll
    for (int k = 0; k < EPT; ++k) {
        int i = my0 + k;
        if (i < e1) {
            int pos = lofs[pb[k]] + pr[k];
            stage[pos] = pay[k];
            bkt[pos] = pb[k];
        }
    }
    __syncthreads();
#pragma unroll
    for (int k = 0; k < EPT; ++k) {
        int j = k * 1024 + t;
        if (j < ne) {
            int b = bkt[j];
            edata_s[gbase[b] + (j - lofs[b])] = stage[j];
        }
    }
}

// ---------------- per-chunk in-degree -> dis, xd ----------------

__global__ __launch_bounds__(256) void k_indeg(const int* __restrict__ edata_d,
                                               const int* __restrict__ off_d,
                                               const float* __restrict__ x,
                                               float* __restrict__ dis,
                                               float4* __restrict__ xd) {
    __shared__ int cnt[CHUNK];
    int t = threadIdx.x;
    int b = blockIdx.x;
    if (t < CHUNK) cnt[t] = 0;
    __syncthreads();
    int e0 = off_d[b], e1 = off_d[b + 1];
    int i = e0 + t * 4;
    // 4-contiguous per thread; stride 1024
    for (; i + 3 < e1; i += 1024) {
        int p0 = edata_d[i], p1 = edata_d[i + 1], p2 = edata_d[i + 2], p3 = edata_d[i + 3];
        atomicAdd(&cnt[p0 >> 17], 1);
        atomicAdd(&cnt[p1 >> 17], 1);
        atomicAdd(&cnt[p2 >> 17], 1);
        atomicAdd(&cnt[p3 >> 17], 1);
    }
    for (; i < e1; ++i) atomicAdd(&cnt[edata_d[i] >> 17], 1);
    __syncthreads();
    if (t < CHUNK) {
        int node = b * CHUNK + t;
        if (node < N_NODES) {
            float d = rsqrtf((float)(cnt[t] + 1));
            dis[node] = d;
            float4 p;
            p.x = x[node * 3 + 0] * d;
            p.y = x[node * 3 + 1] * d;
            p.z = x[node * 3 + 2] * d;
            p.w = d;
            xd[node] = p;
        }
    }
}

// ---------------- layer-1 aggregation per dst chunk; agg.w = dis ----------------

__global__ __launch_bounds__(256) void k_agg(const int* __restrict__ edata_d,
                                             const int* __restrict__ off_d,
                                             const float4* __restrict__ xd,
                                             float4* __restrict__ agg) {
    __shared__ float ax[CHUNK], ay[CHUNK], az[CHUNK];
    int t = threadIdx.x;
    int b = blockIdx.x;
    if (t < CHUNK) { ax[t] = 0.f; ay[t] = 0.f; az[t] = 0.f; }
    __syncthreads();
    int e0 = off_d[b], e1 = off_d[b + 1];
    int i = e0 + t;
    for (; i + 1792 < e1; i += 2048) {
        int p[8];
        float4 y[8];
#pragma unroll
        for (int k = 0; k < 8; ++k) p[k] = edata_d[i + k * 256];
#pragma unroll
        for (int k = 0; k < 8; ++k) y[k] = xd[p[k] & 0x1FFFF];
#pragma unroll
        for (int k = 0; k < 8; ++k) {
            int dl = p[k] >> 17;
            atomicAdd(&ax[dl], y[k].x);
            atomicAdd(&ay[dl], y[k].y);
            atomicAdd(&az[dl], y[k].z);
        }
    }
    for (; i < e1; i += 256) {
        int p = edata_d[i];
        int dl = p >> 17;
        float4 y = xd[p & 0x1FFFF];
        atomicAdd(&ax[dl], y.x);
        atomicAdd(&ay[dl], y.y);
        atomicAdd(&az[dl], y.z);
    }
    __syncthreads();
    if (t < CHUNK) {
        int node = b * CHUNK + t;
        if (node < N_NODES) {
            float4 self = xd[node];
            float d = self.w;
            float4 o;
            o.x = (ax[t] + self.x) * d;
            o.y = (ay[t] + self.y) * d;
            o.z = (az[t] + self.z) * d;
            o.w = d;
            agg[node] = o;
        }
    }
}

// ---------------- coefficient build + MFMA z contraction (src chunks) ----------------

__global__ __launch_bounds__(256) void k_zgemm(const float4* __restrict__ agg,
                                               const int* __restrict__ edata_s,
                                               const int* __restrict__ off_s,
                                               const int* __restrict__ batch,
                                               const float* __restrict__ dis,
                                               const float* __restrict__ W1,
                                               const float* __restrict__ b1,
                                               float* __restrict__ zpart) {
    __shared__ __align__(16) char smem[(DIM + NG) * UP * 2];   // 52224 B
    __shared__ uint2 agb[CHUNK];                               // bf16x4: (x|y, z|dis), 1 KB
    float* ctile = (float*)smem;                                  // [CHUNK][NG] fp32, 32 KB
    unsigned short* uT = (unsigned short*)smem;                   // [DIM][UP] bf16 (overlays ctile)
    float* ztile = (float*)smem;                                  // [NG][ZP] fp32 (overlays uT post-MFMA)
    unsigned short* cbf = (unsigned short*)(smem + DIM * UP * 2); // [NG][UP] bf16

    int t = threadIdx.x;
    int wave = t >> 6, lane = t & 63;
    int q = lane >> 4, l15 = lane & 15;
    int blk = blockIdx.x;
    int base = blk * CHUNK;

    for (int i = t; i < CHUNK * NG; i += 256) ctile[i] = 0.f;
    if (t < CHUNK) {
        int s = base + t;
        float4 a = (s < N_NODES) ? agg[s] : (float4){0.f, 0.f, 0.f, 0.f};
        uint2 p;
        p.x = (unsigned int)f2bf(a.x) | ((unsigned int)f2bf(a.y) << 16);
        p.y = (unsigned int)f2bf(a.z) | ((unsigned int)f2bf(a.w) << 16);
        agb[t] = p;
    }
    __syncthreads();
    // edge phase: ctile[sl][g] += dis_s * dis_d, x8 unrolled for gather MLP
    int e0 = off_s[blk], e1 = off_s[blk + 1];
    int i = e0 + t;
    for (; i + 1792 < e1; i += 2048) {
        int p[8];
        float dd[8];
#pragma unroll
        for (int k = 0; k < 8; ++k) p[k] = edata_s[i + k * 256];
#pragma unroll
        for (int k = 0; k < 8; ++k) dd[k] = dis[p[k] & 0x1FFFF];
#pragma unroll
        for (int k = 0; k < 8; ++k) {
            int sl = p[k] >> 23;
            float ds = bfhi(agb[sl].y);
            atomicAdd(&ctile[sl * NG + ((p[k] >> 17) & 63)], ds * dd[k]);
        }
    }
    for (; i < e1; i += 256) {
        int p = edata_s[i];
        int sl = p >> 23;
        float ds = bfhi(agb[sl].y);
        atomicAdd(&ctile[sl * NG + ((p >> 17) & 63)], ds * dis[p & 0x1FFFF]);
    }
    if (t < CHUNK) {
        int s = base + t;
        if (s < N_NODES) {
            float w = bfhi(agb[t].y);
            atomicAdd(&ctile[t * NG + batch[s]], w * w);
        }
    }
    __syncthreads();
    // transpose-convert: cbf[g][s] = bf16(ctile[s][g])
    for (int i2 = t; i2 < CHUNK * NG; i2 += 256) {
        int g = i2 & 63, s = i2 >> 6;
        cbf[g * UP + s] = f2bf(ctile[i2]);
    }
    __syncthreads();
    // u compute -> bf16 uT[n][s] (overlays ctile)
    {
        int n = t >> 1;
        int sh = (t & 1) * 64;
        float w0 = W1[n], w1 = W1[DIM + n], w2 = W1[2 * DIM + n], bb = b1[n];
        for (int sp = 0; sp < 64; sp += 2) {
            uint2 pa = agb[sh + sp];
            uint2 pbv = agb[sh + sp + 1];
            float u0 = fmaxf(fmaf(bflo(pa.x), w0, fmaf(bfhi(pa.x), w1, fmaf(bflo(pa.y), w2, bb))), 0.f);
            float u1 = fmaxf(fmaf(bflo(pbv.x), w0, fmaf(bfhi(pbv.x), w1, fmaf(bflo(pbv.y), w2, bb))), 0.f);
            unsigned int pk = (unsigned int)f2bf(u0) | ((unsigned int)f2bf(u1) << 16);
            *(unsigned int*)&uT[n * UP + sh + sp] = pk;
        }
    }
    __syncthreads();
    // MFMA: wave w owns n-tiles {2w, 2w+1} x 4 g-tiles
    f32x4 acc[2][4];
#pragma unroll
    for (int mi = 0; mi < 2; ++mi)
#pragma unroll
        for (int nt = 0; nt < 4; ++nt) acc[mi][nt] = (f32x4){0.f, 0.f, 0.f, 0.f};
#pragma unroll
    for (int ks = 0; ks < 4; ++ks) {
        int s0 = ks * 32 + q * 8;
        union { uint4 r; bf16x8 v; } A0, A1, B;
        A0.r = *(const uint4*)&uT[((2 * wave + 0) * 16 + l15) * UP + s0];
        A1.r = *(const uint4*)&uT[((2 * wave + 1) * 16 + l15) * UP + s0];
#pragma unroll
        for (int nt = 0; nt < 4; ++nt) {
            B.r = *(const uint4*)&cbf[(nt * 16 + l15) * UP + s0];
            acc[0][nt] = __builtin_amdgcn_mfma_f32_16x16x32_bf16(A0.v, B.v, acc[0][nt], 0, 0, 0);
            acc[1][nt] = __builtin_amdgcn_mfma_f32_16x16x32_bf16(A1.v, B.v, acc[1][nt], 0, 0, 0);
        }
    }
    __syncthreads();   // uT reads done; reuse as ztile
#pragma unroll
    for (int mi = 0; mi < 2; ++mi) {
#pragma unroll
        for (int nt = 0; nt < 4; ++nt) {
            int g = nt * 16 + l15;
#pragma unroll
            for (int r = 0; r < 4; ++r) {
                int n = (2 * wave + mi) * 16 + q * 4 + r;
                ztile[g * ZP + n] = acc[mi][nt][r];
            }
        }
    }
    __syncthreads();
    float* zp = zpart + (size_t)blk * (NG * DIM);
    for (int i2 = t; i2 < NG * DIM; i2 += 256)
        zp[i2] = ztile[(i2 >> 7) * ZP + (i2 & 127)];
}

// ---------------- two-stage zpart reduction (float4) ----------------

__global__ __launch_bounds__(256) void k_zred1(const float* __restrict__ zpart,
                                               float* __restrict__ zpart2) {
    int id = blockIdx.x * 256 + threadIdx.x;      // [0, NPART*2048)
    int i4 = id & (2048 - 1);
    int p = id >> 11;
    int b0 = p * 98;
    int b1 = min(b0 + 98, NBUK);
    const float4* base = (const float4*)zpart + i4;
    float4 s0 = {0.f, 0.f, 0.f, 0.f}, s1 = {0.f, 0.f, 0.f, 0.f};
    int b = b0;
    for (; b + 1 < b1; b += 2) {
        float4 a = base[(size_t)(b + 0) * 2048];
        float4 c = base[(size_t)(b + 1) * 2048];
        s0.x += a.x; s0.y += a.y; s0.z += a.z; s0.w += a.w;
        s1.x += c.x; s1.y += c.y; s1.z += c.z; s1.w += c.w;
    }
    for (; b < b1; ++b) {
        float4 a = base[(size_t)b * 2048];
        s0.x += a.x; s0.y += a.y; s0.z += a.z; s0.w += a.w;
    }
    float4 o;
    o.x = s0.x + s1.x; o.y = s0.y + s1.y; o.z = s0.z + s1.z; o.w = s0.w + s1.w;
    ((float4*)zpart2)[(size_t)p * 2048 + i4] = o;
}

// ---------------- head: poolmix (8-way partial sum) + final ----------------

__global__ __launch_bounds__(128) void k_poolmix(const float* __restrict__ zpart2,
                                                 const float* __restrict__ W2,
                                                 const float* __restrict__ b2,
                                                 const int* __restrict__ batch,
                                                 float* __restrict__ embed) {
    __shared__ float zr[DIM];
    __shared__ int se[2];
    int g = blockIdx.x;
    int t = threadIdx.x;
    if (t < 2) {
        int target = g + t;
        int lo = 0, hi = N_NODES;
        while (lo < hi) {
            int mid = (lo + hi) >> 1;
            if (batch[mid] < target) lo = mid + 1; else hi = mid;
        }
        se[t] = lo;
    }
    {
        const float* base = zpart2 + g * DIM + t;
        float acc = 0.f;
#pragma unroll
        for (int p = 0; p < NPART; ++p) acc += base[(size_t)p * (NG * DIM)];
        zr[t] = acc;
    }
    __syncthreads();
    float inv = 1.0f / fmaxf((float)(se[1] - se[0]), 1.0f);
    float acc = 0.f;
#pragma unroll 4
    for (int k = 0; k < DIM; ++k) acc = fmaf(zr[k], W2[k * DIM + t], acc);
    embed[g * DIM + t] = acc * inv + b2[t];
}

__global__ __launch_bounds__(128) void k_final(const float* __restrict__ embed,
                                               const float* __restrict__ Wf,
                                               const float* __restrict__ bf,
                                               float* __restrict__ out) {
    int id = blockIdx.x * 128 + threadIdx.x;
    int g = id >> 9, a = id & 511;
    const float* e = embed + g * DIM;
    float s0 = 0.f, s1 = 0.f, s2 = 0.f, s3 = 0.f;
#pragma unroll
    for (int c = 0; c < DIM; c += 4) {
        s0 = fmaf(e[c + 0], Wf[(c + 0) * ACT + a], s0);
        s1 = fmaf(e[c + 1], Wf[(c + 1) * ACT + a], s1);
        s2 = fmaf(e[c + 2], Wf[(c + 2) * ACT + a], s2);
        s3 = fmaf(e[c + 3], Wf[(c + 3) * ACT + a], s3);
    }
    out[id] = (s0 + s1) + (s2 + s3) + bf[a];
}

// ---------------- launch ----------------

static inline size_t align256(size_t x) { return (x + 255) & ~(size_t)255; }

extern "C" void kernel_launch(void* const* d_in, const int* in_sizes, int n_in,
                              void* d_out, int out_size, void* d_ws, size_t ws_size,
                              hipStream_t stream) {
    const float* x  = (const float*)d_in[0];
    const int*   ei = (const int*)d_in[1];
    const int*   batch = (const int*)d_in[2];
    const float* W1 = (const float*)d_in[3];
    const float* b1 = (const float*)d_in[4];
    const float* W2 = (const float*)d_in[5];
    const float* b2 = (const float*)d_in[6];
    const float* Wf = (const float*)d_in[7];
    const float* bf = (const float*)d_in[8];
    float* out = (float*)d_out;

    const int* src = ei;
    const int* dst = ei + N_EDGES;

    char* ws = (char*)d_ws;
    size_t off = 0;
    int*   hist    = (int*)(ws + off);   off = align256(off + (size_t)NBLK_E * NBUK2 * 4);
    int*   colsum  = (int*)(ws + off);   off = align256(off + NBUK2 * 4);
    int*   off_d   = (int*)(ws + off);   off = align256(off + (NBUK + 1) * 4);
    int*   off_s   = (int*)(ws + off);   off = align256(off + (NBUK + 1) * 4);
    int*   edata_d = (int*)(ws + off);   off = align256(off + (size_t)N_EDGES * 4);
    int*   edata_s = (int*)(ws + off);   off = align256(off + (size_t)N_EDGES * 4);
    float* dis     = (float*)(ws + off); off = align256(off + N_NODES * 4);
    float4* xd     = (float4*)(ws + off); off = align256(off + (size_t)N_NODES * 16);
    float4* agg    = (float4*)(ws + off); off = align256(off + (size_t)N_NODES * 16);
    float* zpart   = (float*)(ws + off); off = align256(off + (size_t)NBUK * NG * DIM * 4);
    float* zpart2  = (float*)(ws + off); off = align256(off + (size_t)NPART * NG * DIM * 4);
    float* embed   = (float*)(ws + off); off = align256(off + NG * DIM * 4);

    k_hist<<<NBLK_E, 512, 0, stream>>>(src, dst, hist);
    k_bscanA<<<NBUK2, 256, 0, stream>>>(hist, colsum);
    k_bscanB<<<1, 1024, 0, stream>>>(colsum, off_d, off_s);
    k_bfill<<<NBLK_E, 1024, 0, stream>>>(src, dst, batch, hist, off_d, off_s, edata_d, edata_s);

    k_indeg<<<NBUK, 256, 0, stream>>>(edata_d, off_d, x, dis, xd);
    k_agg<<<NBUK, 256, 0, stream>>>(edata_d, off_d, xd, agg);
    k_zgemm<<<NBUK, 256, 0, stream>>>(agg, edata_s, off_s, batch, dis, W1, b1, zpart);
    k_zred1<<<NPART * NG * DIM / 1024, 256, 0, stream>>>(zpart, zpart2);

    k_poolmix<<<NG, 128, 0, stream>>>(zpart2, W2, b2, batch, embed);
    k_final<<<NG * ACT / 128, 128, 0, stream>>>(embed, Wf, bf, out);
}